// Round 4
// baseline (627.514 us; speedup 1.0000x reference)
//
#include <hip/hip_runtime.h>

// VFE fused kernel, round 6: round-4 structure, DPP reduce replaced with
// __shfl_xor width-8 butterfly (battle-tested on this harness in round 2;
// xor addressing has no read-direction ambiguity — the round-3 failure mode).
// Rounds 4/5 never ran (broker container failures).
//
// B=32768 voxels, P=32 points, IN=7, D2=64, OUT=128 channels per point.
//   local_f[b,p,c] = sum_k x[b,p,k]*W[c,k] + bias[c]          (c in [0,64))
//   global_f[b,g]  = max over flat local_f[b] range [32g,32g+32); g = 2p+half
//   out word [b, p*128 + ce]: ce<64 -> local_f[b,p,ce]; ce>=64 -> global_f[b,ce-64]
//
// Structure:
//  - thread t: point p = t>>3, quad-group g = t&7; owns channels {4g..4g+3} and
//    {32+4g..32+4g+3}. W rows in registers (L1-hot aligned float4 loads).
//  - x[b,p,*] read directly from global (8-lane broadcast), no staging barrier.
//  - local_f stored DIRECTLY to global as float4; each wave store instruction
//    covers full 64B lines (no LDS round trip, no partial-line RMW).
//  - group max: in-thread max4, then xor-butterfly over the 8-lane point group
//    (__shfl_xor masks 1,2,4 with width 8). Lane g==0 writes float2 {mLo,mHi}.
//  - one barrier; global-feature section written as 2 float4 stores/thread.

#define B_VOX 32768

__device__ __forceinline__ float group8_max(float v) {
    v = fmaxf(v, __shfl_xor(v, 1, 8));
    v = fmaxf(v, __shfl_xor(v, 2, 8));
    v = fmaxf(v, __shfl_xor(v, 4, 8));
    return v;
}

__global__ __launch_bounds__(256) void vfe_kernel(
    const float* __restrict__ x,
    const float* __restrict__ W,
    const float* __restrict__ bias,
    float* __restrict__ out)
{
    __shared__ alignas(16) float sg[64];     // global_f for this voxel

    const int t = threadIdx.x;               // 0..255
    const int b = blockIdx.x;                // voxel id
    const int p = t >> 3;                    // point 0..31 (8 lanes per point)
    const int g = t & 7;                     // channel-quad group 0..7

    // ---- x row p: 7 floats, 8 lanes share the address (broadcast, L2-coalesced) ----
    const float* xr = x + (size_t)b * 224 + p * 7;
    const float x0 = xr[0], x1 = xr[1], x2 = xr[2], x3 = xr[3];
    const float x4 = xr[4], x5 = xr[5], x6 = xr[6];

    // ---- W rows {4g..4g+3} and {32+4g..32+4g+3}: 2 x 28 floats, 16B-aligned ----
    const float4* Wlo = (const float4*)(W + 28 * g);
    const float4* Whi = (const float4*)(W + 224 + 28 * g);
    float wl[28], wh[28];
    #pragma unroll
    for (int q = 0; q < 7; ++q) {
        const float4 a = Wlo[q];
        wl[4*q+0] = a.x; wl[4*q+1] = a.y; wl[4*q+2] = a.z; wl[4*q+3] = a.w;
        const float4 c = Whi[q];
        wh[4*q+0] = c.x; wh[4*q+1] = c.y; wh[4*q+2] = c.z; wh[4*q+3] = c.w;
    }
    const float4 blo = *(const float4*)(bias + 4 * g);
    const float4 bhi = *(const float4*)(bias + 32 + 4 * g);
    const float bl[4] = {blo.x, blo.y, blo.z, blo.w};
    const float bh[4] = {bhi.x, bhi.y, bhi.z, bhi.w};

    // ---- 56 FMA: 8 channels x 7 inputs ----
    float accLo[4], accHi[4];
    #pragma unroll
    for (int j = 0; j < 4; ++j) {
        float a = bl[j];
        a = fmaf(x0, wl[7*j+0], a);
        a = fmaf(x1, wl[7*j+1], a);
        a = fmaf(x2, wl[7*j+2], a);
        a = fmaf(x3, wl[7*j+3], a);
        a = fmaf(x4, wl[7*j+4], a);
        a = fmaf(x5, wl[7*j+5], a);
        a = fmaf(x6, wl[7*j+6], a);
        accLo[j] = a;
        float c = bh[j];
        c = fmaf(x0, wh[7*j+0], c);
        c = fmaf(x1, wh[7*j+1], c);
        c = fmaf(x2, wh[7*j+2], c);
        c = fmaf(x3, wh[7*j+3], c);
        c = fmaf(x4, wh[7*j+4], c);
        c = fmaf(x5, wh[7*j+5], c);
        c = fmaf(x6, wh[7*j+6], c);
        accHi[j] = c;
    }

    // ---- locals straight to global: full 64B lines per wave store instruction ----
    float* ob = out + (size_t)b * 4096;
    *(float4*)(ob + p * 128 + 4 * g)      = make_float4(accLo[0], accLo[1], accLo[2], accLo[3]);
    *(float4*)(ob + p * 128 + 32 + 4 * g) = make_float4(accHi[0], accHi[1], accHi[2], accHi[3]);

    // ---- group max: 8 lanes (g=0..7) of point p each hold 4 channels of a half.
    //      In-thread max4, then xor-butterfly across the aligned 8-lane group.
    float mLo = group8_max(fmaxf(fmaxf(accLo[0], accLo[1]), fmaxf(accLo[2], accLo[3])));
    float mHi = group8_max(fmaxf(fmaxf(accHi[0], accHi[1]), fmaxf(accHi[2], accHi[3])));
    if (g == 0)
        *(float2*)&sg[2 * p] = make_float2(mLo, mHi);   // sg[2p+half] = global_f[2p+half]

    __syncthreads();

    // ---- global-feature section: out[b, p0*128+64+4j .. +3] = sg[4j..4j+3]
    const int j4 = t & 15;
    const int p0 = t >> 4;
    const float4 g4 = *(const float4*)&sg[4 * j4];
    *(float4*)(ob + p0 * 128 + 64 + 4 * j4)        = g4;
    *(float4*)(ob + (p0 + 16) * 128 + 64 + 4 * j4) = g4;
}

extern "C" void kernel_launch(void* const* d_in, const int* in_sizes, int n_in,
                              void* d_out, int out_size, void* d_ws, size_t ws_size,
                              hipStream_t stream) {
    const float* x    = (const float*)d_in[0];   // [32768, 32, 7]
    const float* W    = (const float*)d_in[1];   // [64, 7]
    const float* bias = (const float*)d_in[2];   // [64]
    float* out        = (float*)d_out;           // [32768, 128, 32] flat

    vfe_kernel<<<B_VOX, 256, 0, stream>>>(x, W, bias, out);
}